// Round 7
// baseline (1787.069 us; speedup 1.0000x reference)
//
#include <hip/hip_runtime.h>
#include <math.h>

#define Bb 32
#define Ss 512
#define Dd 512
#define Hh 8
#define NLn 6
#define DFf 2048

typedef unsigned short u16;
typedef __attribute__((ext_vector_type(8))) short bf16x8;
typedef __attribute__((ext_vector_type(4))) float f32x4;

__device__ __forceinline__ u16 f2bf(float f){
  union { float f; unsigned u; } x; x.f = f;
  return (u16)((x.u + 0x7fffu + ((x.u >> 16) & 1u)) >> 16);
}
__device__ __forceinline__ float gelu_f(float x){
  return 0.5f * x * (1.0f + erff(x * 0.7071067811865475f));
}
__device__ __forceinline__ f32x4 mfma16(bf16x8 a, bf16x8 b, f32x4 c){
  return __builtin_amdgcn_mfma_f32_16x16x32_bf16(a, b, c, 0, 0, 0);
}
__device__ __forceinline__ void gload16(const void* g, void* l){
  void* gg = (void*)g;
  __builtin_amdgcn_global_load_lds((__attribute__((address_space(1))) void*)gg,
                                   (__attribute__((address_space(3))) void*)l, 16, 0, 0);
}

// ---------------- f32 -> bf16 cast (plain weights) ----------------
__global__ void cast_kernel(const float* __restrict__ src, u16* __restrict__ dst, int n){
  int i = (blockIdx.x * 256 + threadIdx.x) * 4;
  if (i < n){
    float4 v = *(const float4*)&src[i];
    ushort4 o; o.x = f2bf(v.x); o.y = f2bf(v.y); o.z = f2bf(v.z); o.w = f2bf(v.w);
    *(ushort4*)&dst[i] = o;
  }
}

// cast Wq/Wk/Wv [NL][512][512] into fused [NL][1536][512] at row-block blk
__global__ void cast_qkv_kernel(const float* __restrict__ src, u16* __restrict__ dst, int blk){
  int i = (blockIdx.x * 256 + threadIdx.x) * 4;
  if (i < NLn*Dd*Dd){
    int l = i >> 18, r = i & (Dd*Dd - 1);
    float4 v = *(const float4*)&src[i];
    ushort4 o; o.x = f2bf(v.x); o.y = f2bf(v.y); o.z = f2bf(v.z); o.w = f2bf(v.w);
    *(ushort4*)&dst[(size_t)l*(3*Dd*Dd) + (size_t)blk*Dd*Dd + r] = o;
  }
}

__global__ void bias_concat_kernel(const float* __restrict__ bq, const float* __restrict__ bk,
                                   const float* __restrict__ bv, float* __restrict__ dst){
  int i = blockIdx.x*256 + threadIdx.x;   // NL*512
  if (i < NLn*Dd){
    int l = i >> 9, r = i & 511;
    float* d = dst + (size_t)l*1536;
    d[r] = bq[i]; d[512+r] = bk[i]; d[1024+r] = bv[i];
  }
}

// ---------------- tau / delta projector (outputs pre-scaled, base-2, -16 shift) ----------------
#define SCL 0.180336880542795f   // 0.125 * log2(e)
__global__ void proj_kernel(const float* __restrict__ x_enc,
                            const float* __restrict__ Wtc, const float* __restrict__ Wt1, const float* __restrict__ bt1,
                            const float* __restrict__ Wt2, const float* __restrict__ bt2, const float* __restrict__ Wt3,
                            const float* __restrict__ Wdc, const float* __restrict__ Wd1, const float* __restrict__ bd1,
                            const float* __restrict__ Wd2, const float* __restrict__ bd2, const float* __restrict__ Wd3,
                            float* __restrict__ tau2, float* __restrict__ delta2){
  const int b = blockIdx.x, t = threadIdx.x;
  __shared__ float red[8][128];
  __shared__ float fv[8];
  __shared__ float ftau[4], fdel[4], h1t[128], h1d[128], h2t[128], h2d[128];
  float s0=0,s1=0,q0=0,q1=0,tc0=0,tc1=0,dc0=0,dc1=0;
  for (int s = t; s < Ss; s += 128){
    float x0 = x_enc[(b*Ss + s)*2 + 0];
    float x1 = x_enc[(b*Ss + s)*2 + 1];
    float wt0 = Wtc[s*3], wt1v = Wtc[s*3+1], wt2v = Wtc[s*3+2];
    float wd0 = Wdc[s*3], wd1v = Wdc[s*3+1], wd2v = Wdc[s*3+2];
    s0 += x0; s1 += x1; q0 += x0*x0; q1 += x1*x1;
    tc0 += x1*(wt0+wt2v) + x0*wt1v;
    tc1 += x0*(wt0+wt2v) + x1*wt1v;
    dc0 += x1*(wd0+wd2v) + x0*wd1v;
    dc1 += x0*(wd0+wd2v) + x1*wd1v;
  }
  red[0][t]=s0; red[1][t]=s1; red[2][t]=q0; red[3][t]=q1;
  red[4][t]=tc0; red[5][t]=tc1; red[6][t]=dc0; red[7][t]=dc1;
  __syncthreads();
  if (t < 8){ float a = 0; for (int i = 0; i < 128; i++) a += red[t][i]; fv[t] = a; }
  __syncthreads();
  if (t == 0){
    float m0 = fv[0]/Ss, m1 = fv[1]/Ss;
    float v0 = fv[2]/Ss - m0*m0, v1 = fv[3]/Ss - m1*m1;
    ftau[0]=fv[4]; ftau[1]=fv[5]; ftau[2]=sqrtf(v0+1e-5f); ftau[3]=sqrtf(v1+1e-5f);
    fdel[0]=fv[6]; fdel[1]=fv[7]; fdel[2]=m0; fdel[3]=m1;
  }
  __syncthreads();
  {
    float a = bt1[t], ad = bd1[t];
    #pragma unroll
    for (int j = 0; j < 4; j++){ a += Wt1[t*4+j]*ftau[j]; ad += Wd1[t*4+j]*fdel[j]; }
    h1t[t] = fmaxf(a, 0.f); h1d[t] = fmaxf(ad, 0.f);
  }
  __syncthreads();
  {
    float a = bt2[t], ad = bd2[t];
    for (int j = 0; j < 128; j++){ a += Wt2[t*128+j]*h1t[j]; ad += Wd2[t*128+j]*h1d[j]; }
    h2t[t] = fmaxf(a, 0.f); h2d[t] = fmaxf(ad, 0.f);
  }
  __syncthreads();
  if (t == 0){
    float z = 0; for (int j = 0; j < 128; j++) z += Wt3[j]*h2t[j];
    tau2[b] = expf(z) * SCL;
  }
  for (int s = t; s < Ss; s += 128){
    float z = 0; for (int j = 0; j < 128; j++) z += Wd3[s*128+j]*h2d[j];
    delta2[b*Ss + s] = z * SCL - 16.0f;
  }
}

// ---------------- embedding: circular conv + positional encoding ----------------
__global__ void embed_kernel(const float* __restrict__ xe, const float* __restrict__ Wemb,
                             float* __restrict__ xf, u16* __restrict__ xb){
  const int bs = blockIdx.x;          // b*S + s
  const int b = bs >> 9, s = bs & 511;
  const int t = threadIdx.x;          // 128 threads, 4 d each
  const int sm = (s + 511) & 511, sp = (s + 1) & 511;
  const float xm0 = xe[(b*Ss + sm)*2],   xm1 = xe[(b*Ss + sm)*2 + 1];
  const float x00 = xe[(b*Ss + s )*2],   x01 = xe[(b*Ss + s )*2 + 1];
  const float xp0 = xe[(b*Ss + sp)*2],   xp1 = xe[(b*Ss + sp)*2 + 1];
  #pragma unroll
  for (int dd = 0; dd < 4; dd++){
    const int d = t*4 + dd;
    const float* wd = Wemb + d*6;       // (D,2,3)
    float a = xm0*wd[0] + x00*wd[1] + xp0*wd[2]
            + xm1*wd[3] + x01*wd[4] + xp1*wd[5];
    const int i2 = d & ~1;
    float div = expf((float)i2 * (-9.210340371976184f / 512.0f));
    float ang = (float)s * div;
    float pe = (d & 1) ? cosf(ang) : sinf(ang);
    float v = a + pe;
    xf[(size_t)bs*Dd + d] = v;
    xb[(size_t)bs*Dd + d] = f2bf(v);
  }
}

// ---------------- GEMM: C[M,N] = A[M,K](bf16) * W[N,K]^T(bf16) + bias ----------------
// Round-2 proven 2-barrier loop (compiler-scheduled, single 16KB buffer) +
// XCD-bijective 1D grid swizzle (FETCH halved) + LDS-routed coalesced bf16
// epilogue (WRITE halved). EPI: 0 = f32 out, 1 = bf16 out, 2 = bf16+gelu.
template<int EPI>
__global__ __launch_bounds__(256) void gemm_bt(const u16* __restrict__ A, const u16* __restrict__ W,
                                               const float* __restrict__ bias, void* __restrict__ Cv,
                                               int M, int N, int K, int ntx){
  __shared__ __attribute__((aligned(16))) u16 SM[2*4096];  // As | Bs (128x32 each)
  u16* As = SM;
  u16* Bs = SM + 4096;
  const int tid = threadIdx.x;
  const int w = tid >> 6, l = tid & 63;
  const int wr = w >> 1, wc = w & 1;
  // ---- XCD-aware bijective tile swizzle: each XCD owns contiguous M-panels ----
  const int nwg = gridDim.x;
  const int cpx = nwg >> 3;
  const int lin = blockIdx.x;
  const int g = (lin & 7)*cpx + (lin >> 3);
  const int by = g / ntx;
  const int bx = g - by*ntx;
  const long bm0 = (long)by * 128;
  const long bn0 = (long)bx * 128;
  // ---- staging addresses ----
  const int lr = l >> 2, lc = l & 3;
  const u16* Ag = A + (bm0 + w*32 + lr) * (long)K + lc*8;
  const u16* Bg = W + (bn0 + w*32 + lr) * (long)K + lc*8;
  u16* AsW = As + w*1024;
  u16* BsW = Bs + w*1024;
  f32x4 acc[4][4] = {};
  const int aro = wr*64 + (l & 15);
  const int bro = wc*64 + (l & 15);
  const int k8 = (l >> 4) * 8;
  for (int kt = 0; kt < K; kt += 32){
    gload16(Ag + kt,               AsW);
    gload16(Ag + kt + 16*(long)K,  AsW + 512);
    gload16(Bg + kt,               BsW);
    gload16(Bg + kt + 16*(long)K,  BsW + 512);
    __syncthreads();   // compiler drains vmcnt: staged tile visible
    bf16x8 af[4], bfv[4];
    #pragma unroll
    for (int mi = 0; mi < 4; mi++) af[mi] = *(const bf16x8*)&As[(aro + mi*16)*32 + k8];
    #pragma unroll
    for (int ni = 0; ni < 4; ni++) bfv[ni] = *(const bf16x8*)&Bs[(bro + ni*16)*32 + k8];
    #pragma unroll
    for (int mi = 0; mi < 4; mi++)
      #pragma unroll
      for (int ni = 0; ni < 4; ni++)
        acc[mi][ni] = mfma16(af[mi], bfv[ni], acc[mi][ni]);
    __syncthreads();   // all waves done reading before next stage overwrites
  }
  if (EPI == 0){
    // f32 direct stores (64B segments per 16 lanes, no amplification)
    const long rbase = bm0 + wr*64 + (l >> 4)*4;
    const int cbase = (int)bn0 + wc*64 + (l & 15);
    #pragma unroll
    for (int ni = 0; ni < 4; ni++){
      const int c = cbase + ni*16;
      const float bvv = bias[c];
      #pragma unroll
      for (int mi = 0; mi < 4; mi++)
        #pragma unroll
        for (int j = 0; j < 4; j++)
          ((float*)Cv)[(size_t)(rbase + mi*16 + j) * N + c] = acc[mi][ni][j] + bvv;
    }
  } else {
    // bf16: route through LDS for coalesced 256B row stores
    u16* CT = SM;                 // 64x128 u16 = 16 KB (reuses As|Bs)
    float bvv[4];
    #pragma unroll
    for (int ni = 0; ni < 4; ni++) bvv[ni] = bias[bn0 + wc*64 + ni*16 + (l & 15)];
    u16* Cu = (u16*)Cv;
    #pragma unroll
    for (int h = 0; h < 2; h++){
      __syncthreads();
      #pragma unroll
      for (int mi2 = 0; mi2 < 2; mi2++){
        const int mi = 2*h + mi2;
        #pragma unroll
        for (int ni = 0; ni < 4; ni++){
          #pragma unroll
          for (int j = 0; j < 4; j++){
            float v = acc[mi][ni][j] + bvv[ni];
            if (EPI == 2) v = gelu_f(v);
            CT[(wr*32 + mi2*16 + (l >> 4)*4 + j)*128 + wc*64 + ni*16 + (l & 15)] = f2bf(v);
          }
        }
      }
      __syncthreads();
      #pragma unroll
      for (int p = 0; p < 4; p++){
        const int r = (tid >> 4) + p*16;
        const long grow = bm0 + (r >> 5)*64 + h*32 + (r & 31);
        *(bf16x8*)&Cu[(size_t)grow * N + bn0 + (tid & 15)*8] =
            *(const bf16x8*)&CT[r*128 + (tid & 15)*8];
      }
    }
  }
}

// ---------------- fused flash attention, one block per (b,h) ----------------
__global__ __launch_bounds__(512, 2) void attn_kernel(const u16* __restrict__ qkv,
                                                      const float* __restrict__ tau2,
                                                      const float* __restrict__ delta2,
                                                      u16* __restrict__ Ob){
  const int bid = blockIdx.x;
  const int h = bid & 7, b = bid >> 3;
  const int t = threadIdx.x, w = t >> 6, l = t & 63;
  const int l15 = l & 15, l4 = l >> 4;
  __shared__ __attribute__((aligned(16))) u16 Ks[512*64];      // 64 KB, XOR swizzle
  __shared__ __attribute__((aligned(16))) u16 Vt[64*520];      // 65 KB, pad 520
  __shared__ __attribute__((aligned(16))) u16 Ps[8][16*72];    // 18 KB, per-wave
  const size_t qkvbase = ((size_t)b*Ss)*1536 + h*64;
  {
    const u16* Kg = qkv + qkvbase + 512  + (size_t)t*1536;
    const u16* Vg = qkv + qkvbase + 1024 + (size_t)t*1536;
    #pragma unroll
    for (int c = 0; c < 8; c++){
      bf16x8 kv = *(const bf16x8*)&Kg[c*8];
      const int byte = t*128 + ((c*16) ^ ((t & 7) << 4));
      *(bf16x8*)((char*)Ks + byte) = kv;
    }
    union { bf16x8 v[8]; u16 e[64]; } vv;
    #pragma unroll
    for (int c = 0; c < 8; c++) vv.v[c] = *(const bf16x8*)&Vg[c*8];
    #pragma unroll
    for (int e = 0; e < 64; e++) Vt[e*520 + t] = vv.e[e];
  }
  const int q0 = w*64;
  bf16x8 qa[4][2];
  #pragma unroll
  for (int mi = 0; mi < 4; mi++)
    #pragma unroll
    for (int ks = 0; ks < 2; ks++)
      qa[mi][ks] = *(const bf16x8*)&qkv[qkvbase + (size_t)(q0 + mi*16 + l15)*1536 + ks*32 + l4*8];
  const float ts = tau2[b];
  bf16x8 ones8;
  #pragma unroll
  for (int i = 0; i < 8; i++) ones8[i] = (short)0x3F80;
  __syncthreads();

  f32x4 Oa[4][4] = {};
  f32x4 Ls[4] = {};
  u16* PsW = Ps[w];
  for (int kt = 0; kt < 8; kt++){
    f32x4 sc[4][4] = {};
    #pragma unroll
    for (int ni = 0; ni < 4; ni++){
      const int krow = kt*64 + ni*16 + l15;
      const int swz = (krow & 7) << 4;
      bf16x8 kf0 = *(const bf16x8*)((const char*)Ks + krow*128 + ((l4*16)      ^ swz));
      bf16x8 kf1 = *(const bf16x8*)((const char*)Ks + krow*128 + ((64 + l4*16) ^ swz));
      #pragma unroll
      for (int mi = 0; mi < 4; mi++){
        sc[mi][ni] = mfma16(qa[mi][0], kf0, sc[mi][ni]);
        sc[mi][ni] = mfma16(qa[mi][1], kf1, sc[mi][ni]);
      }
    }
    float dl[4];
    #pragma unroll
    for (int ni = 0; ni < 4; ni++) dl[ni] = delta2[b*Ss + kt*64 + ni*16 + l15];
    bf16x8 pa[4][2];
    #pragma unroll
    for (int mi = 0; mi < 4; mi++){
      #pragma unroll
      for (int ni = 0; ni < 4; ni++){
        #pragma unroll
        for (int j = 0; j < 4; j++){
          float p = exp2f(ts * sc[mi][ni][j] + dl[ni]);
          PsW[(l4*4 + j)*72 + ni*16 + l15] = f2bf(p);
        }
      }
      pa[mi][0] = *(const bf16x8*)&PsW[l15*72 +      l4*8];
      pa[mi][1] = *(const bf16x8*)&PsW[l15*72 + 32 + l4*8];
    }
    #pragma unroll
    for (int ni = 0; ni < 4; ni++){
      const int vrow = ni*16 + l15;
      bf16x8 vf0 = *(const bf16x8*)&Vt[vrow*520 + kt*64 +      l4*8];
      bf16x8 vf1 = *(const bf16x8*)&Vt[vrow*520 + kt*64 + 32 + l4*8];
      #pragma unroll
      for (int mi = 0; mi < 4; mi++){
        Oa[mi][ni] = mfma16(pa[mi][0], vf0, Oa[mi][ni]);
        Oa[mi][ni] = mfma16(pa[mi][1], vf1, Oa[mi][ni]);
      }
    }
    #pragma unroll
    for (int mi = 0; mi < 4; mi++){
      Ls[mi] = mfma16(pa[mi][0], ones8, Ls[mi]);
      Ls[mi] = mfma16(pa[mi][1], ones8, Ls[mi]);
    }
  }
  const size_t obase = (size_t)b*Ss*Dd + h*64;
  #pragma unroll
  for (int mi = 0; mi < 4; mi++){
    f32x4 rv;
    #pragma unroll
    for (int j = 0; j < 4; j++) rv[j] = 1.0f / Ls[mi][j];
    #pragma unroll
    for (int ni = 0; ni < 4; ni++)
      #pragma unroll
      for (int j = 0; j < 4; j++)
        Ob[obase + (size_t)(q0 + mi*16 + l4*4 + j)*Dd + ni*16 + l15] = f2bf(Oa[mi][ni][j] * rv[j]);
  }
}

// ---------------- fused residual + LayerNorm (float4) ----------------
__global__ void ln_residual_kernel(float* __restrict__ xf, const float* __restrict__ tf,
                                   const float* __restrict__ g, const float* __restrict__ bln,
                                   u16* __restrict__ xb){
  const int row = blockIdx.x, t = threadIdx.x;   // 128 threads
  const size_t base = (size_t)row * Dd + t*4;
  float4 a = *(const float4*)&xf[base];
  const float4 dv = *(const float4*)&tf[base];
  a.x += dv.x; a.y += dv.y; a.z += dv.z; a.w += dv.w;
  float sum = a.x + a.y + a.z + a.w;
  float sq  = a.x*a.x + a.y*a.y + a.z*a.z + a.w*a.w;
  #pragma unroll
  for (int off = 32; off >= 1; off >>= 1){ sum += __shfl_down(sum, off); sq += __shfl_down(sq, off); }
  __shared__ float sh[4];
  const int w = t >> 6, l = t & 63;
  if (l == 0){ sh[w] = sum; sh[2+w] = sq; }
  __syncthreads();
  sum = sh[0] + sh[1]; sq = sh[2] + sh[3];
  const float mean = sum * (1.f/Dd);
  const float var  = sq * (1.f/Dd) - mean*mean;
  const float rstd = rsqrtf(var + 1e-5f);
  const float4 gg = *(const float4*)&g[t*4];
  const float4 bb = *(const float4*)&bln[t*4];
  float4 y;
  y.x = (a.x - mean)*rstd*gg.x + bb.x;
  y.y = (a.y - mean)*rstd*gg.y + bb.y;
  y.z = (a.z - mean)*rstd*gg.z + bb.z;
  y.w = (a.w - mean)*rstd*gg.w + bb.w;
  *(float4*)&xf[base] = y;
  ushort4 o; o.x = f2bf(y.x); o.y = f2bf(y.y); o.z = f2bf(y.z); o.w = f2bf(y.w);
  *(ushort4*)&xb[base] = o;
}

// ---------------- final LN + gelu + Wout dot ----------------
__global__ void final_kernel(const float* __restrict__ xf, const float* __restrict__ gn, const float* __restrict__ bn,
                             const float* __restrict__ Wout, const float* __restrict__ bout,
                             float* __restrict__ out){
  const int row = blockIdx.x, t = threadIdx.x;
  const size_t base = (size_t)row * Dd;
  const int i = t*2;
  float x0 = xf[base+i], x1 = xf[base+i+1];
  float sum = x0 + x1, sq = x0*x0 + x1*x1;
  #pragma unroll
  for (int off = 32; off >= 1; off >>= 1){ sum += __shfl_down(sum, off); sq += __shfl_down(sq, off); }
  __shared__ float sh[8];
  __shared__ float sh2[4];
  const int w = t >> 6, l = t & 63;
  if (l == 0){ sh[w] = sum; sh[4+w] = sq; }
  __syncthreads();
  sum = sh[0]+sh[1]+sh[2]+sh[3];
  sq  = sh[4]+sh[5]+sh[6]+sh[7];
  const float mean = sum * (1.f/Dd);
  const float var  = sq * (1.f/Dd) - mean*mean;
  const float rstd = rsqrtf(var + 1e-5f);
  float y0 = (x0 - mean)*rstd*gn[i]   + bn[i];
  float y1 = (x1 - mean)*rstd*gn[i+1] + bn[i+1];
  float p = gelu_f(y0)*Wout[i] + gelu_f(y1)*Wout[i+1];
  #pragma unroll
  for (int off = 32; off >= 1; off >>= 1) p += __shfl_down(p, off);
  if (l == 0) sh2[w] = p;
  __syncthreads();
  if (t == 0) out[row] = sh2[0]+sh2[1]+sh2[2]+sh2[3] + bout[0];
}

extern "C" void kernel_launch(void* const* d_in, const int* in_sizes, int n_in,
                              void* d_out, int out_size, void* d_ws, size_t ws_size,
                              hipStream_t stream){
  (void)in_sizes; (void)n_in; (void)out_size; (void)ws_size;
  const float* x_enc = (const float*)d_in[0];
  const float* W_emb = (const float*)d_in[1];
  const float* Wq  = (const float*)d_in[2];
  const float* bq  = (const float*)d_in[3];
  const float* Wk  = (const float*)d_in[4];
  const float* bk  = (const float*)d_in[5];
  const float* Wv  = (const float*)d_in[6];
  const float* bvp = (const float*)d_in[7];
  const float* Wo  = (const float*)d_in[8];
  const float* bo  = (const float*)d_in[9];
  const float* Wc1 = (const float*)d_in[10];
  const float* bc1 = (const float*)d_in[11];
  const float* Wc2 = (const float*)d_in[12];
  const float* bc2 = (const float*)d_in[13];
  const float* g1  = (const float*)d_in[14];
  const float* be1 = (const float*)d_in[15];
  const float* g2  = (const float*)d_in[16];
  const float* be2 = (const float*)d_in[17];
  const float* gn  = (const float*)d_in[18];
  const float* bn  = (const float*)d_in[19];
  const float* Wout= (const float*)d_in[20];
  const float* bout= (const float*)d_in[21];
  const float* Wtc = (const float*)d_in[22];
  const float* Wt1 = (const float*)d_in[23];
  const float* bt1 = (const float*)d_in[24];
  const float* Wt2 = (const float*)d_in[25];
  const float* bt2 = (const float*)d_in[26];
  const float* Wt3 = (const float*)d_in[27];
  const float* Wdc = (const float*)d_in[28];
  const float* Wd1 = (const float*)d_in[29];
  const float* bd1 = (const float*)d_in[30];
  const float* Wd2 = (const float*)d_in[31];
  const float* bd2 = (const float*)d_in[32];
  const float* Wd3 = (const float*)d_in[33];

  char* ws = (char*)d_ws;
  size_t off = 0;
  auto alloc = [&](size_t nbytes) -> void* {
    void* p = ws + off; off += (nbytes + 255) & ~(size_t)255; return p;
  };
  const size_t BSD = (size_t)Bb*Ss*Dd;
  u16* Wqkv_b = (u16*)alloc((size_t)NLn*3*Dd*Dd*2);
  u16* Wo_b   = (u16*)alloc((size_t)NLn*Dd*Dd*2);
  u16* Wc1_b  = (u16*)alloc((size_t)NLn*DFf*Dd*2);
  u16* Wc2_b  = (u16*)alloc((size_t)NLn*Dd*DFf*2);
  float* bqkv = (float*)alloc((size_t)NLn*3*Dd*4);
  float* xf   = (float*)alloc(BSD*4);
  u16*   xb   = (u16*)alloc(BSD*2);
  u16*   qkvb = (u16*)alloc(BSD*3*2);
  u16*   ab   = (u16*)alloc(BSD*2);
  float* tf   = (float*)alloc(BSD*4);
  u16*   hb   = (u16*)alloc((size_t)Bb*Ss*DFf*2);
  float* tau2   = (float*)alloc(Bb*4);
  float* delta2 = (float*)alloc((size_t)Bb*Ss*4);

  const int nW = NLn*Dd*Dd;       // 1,572,864
  const int nC = NLn*DFf*Dd;      // 6,291,456
  cast_qkv_kernel<<<nW/1024, 256, 0, stream>>>(Wq, Wqkv_b, 0);
  cast_qkv_kernel<<<nW/1024, 256, 0, stream>>>(Wk, Wqkv_b, 1);
  cast_qkv_kernel<<<nW/1024, 256, 0, stream>>>(Wv, Wqkv_b, 2);
  cast_kernel<<<nW/1024, 256, 0, stream>>>(Wo,  Wo_b,  nW);
  cast_kernel<<<nC/1024, 256, 0, stream>>>(Wc1, Wc1_b, nC);
  cast_kernel<<<nC/1024, 256, 0, stream>>>(Wc2, Wc2_b, nC);
  bias_concat_kernel<<<(NLn*Dd + 255)/256, 256, 0, stream>>>(bq, bk, bvp, bqkv);

  proj_kernel<<<Bb, 128, 0, stream>>>(x_enc, Wtc, Wt1, bt1, Wt2, bt2, Wt3,
                                      Wdc, Wd1, bd1, Wd2, bd2, Wd3, tau2, delta2);
  embed_kernel<<<Bb*Ss, 128, 0, stream>>>(x_enc, W_emb, xf, xb);

  const int M = Bb*Ss;
  const int nQKV = (3*Dd/128)*(M/128);   // 12*128 = 1536
  const int n512 = (Dd/128)*(M/128);     // 4*128  = 512
  const int nFF1 = (DFf/128)*(M/128);    // 16*128 = 2048
  for (int lyr = 0; lyr < NLn; lyr++){
    const u16* wqkv = Wqkv_b + (size_t)lyr*3*Dd*Dd;
    const u16* wo = Wo_b  + (size_t)lyr*Dd*Dd;
    const u16* w1 = Wc1_b + (size_t)lyr*DFf*Dd;
    const u16* w2 = Wc2_b + (size_t)lyr*Dd*DFf;
    gemm_bt<1><<<nQKV, 256, 0, stream>>>(xb, wqkv, bqkv + (size_t)lyr*3*Dd, qkvb, M, 3*Dd, Dd, 3*Dd/128);
    attn_kernel<<<Bb*Hh, 512, 0, stream>>>(qkvb, tau2, delta2, ab);
    gemm_bt<0><<<n512, 256, 0, stream>>>(ab, wo, bo + lyr*Dd, tf, M, Dd, Dd, Dd/128);
    ln_residual_kernel<<<M, 128, 0, stream>>>(xf, tf, g1 + lyr*Dd, be1 + lyr*Dd, xb);
    gemm_bt<2><<<nFF1, 256, 0, stream>>>(xb, w1, bc1 + lyr*DFf, hb, M, DFf, Dd, DFf/128);
    gemm_bt<0><<<n512, 256, 0, stream>>>(hb, w2, bc2 + lyr*Dd, tf, M, Dd, DFf, Dd/128);
    ln_residual_kernel<<<M, 128, 0, stream>>>(xf, tf, g2 + lyr*Dd, be2 + lyr*Dd, xb);
  }
  final_kernel<<<M, 256, 0, stream>>>(xf, gn, bn, Wout, bout, (float*)d_out);
}

// Round 8
// 1670.366 us; speedup vs baseline: 1.0699x; 1.0699x over previous
//
#include <hip/hip_runtime.h>
#include <math.h>

#define Bb 32
#define Ss 512
#define Dd 512
#define Hh 8
#define NLn 6
#define DFf 2048

typedef unsigned short u16;
typedef __attribute__((ext_vector_type(8))) short bf16x8;
typedef __attribute__((ext_vector_type(4))) float f32x4;

__device__ __forceinline__ u16 f2bf(float f){
  union { float f; unsigned u; } x; x.f = f;
  return (u16)((x.u + 0x7fffu + ((x.u >> 16) & 1u)) >> 16);
}
__device__ __forceinline__ float gelu_f(float x){
  return 0.5f * x * (1.0f + erff(x * 0.7071067811865475f));
}
// tanh-form gelu: 1 hw exp2 + div, max |diff vs exact| ~3e-3
__device__ __forceinline__ float gelu_t(float x){
  return x / (1.0f + exp2f(-2.3022588f * (x + 0.044715f * x * x * x)));
}
__device__ __forceinline__ f32x4 mfma16(bf16x8 a, bf16x8 b, f32x4 c){
  return __builtin_amdgcn_mfma_f32_16x16x32_bf16(a, b, c, 0, 0, 0);
}
__device__ __forceinline__ void gload16(const void* g, void* l){
  void* gg = (void*)g;
  __builtin_amdgcn_global_load_lds((__attribute__((address_space(1))) void*)gg,
                                   (__attribute__((address_space(3))) void*)l, 16, 0, 0);
}

// ---------------- f32 -> bf16 cast (plain weights) ----------------
__global__ void cast_kernel(const float* __restrict__ src, u16* __restrict__ dst, int n){
  int i = (blockIdx.x * 256 + threadIdx.x) * 4;
  if (i < n){
    float4 v = *(const float4*)&src[i];
    ushort4 o; o.x = f2bf(v.x); o.y = f2bf(v.y); o.z = f2bf(v.z); o.w = f2bf(v.w);
    *(ushort4*)&dst[i] = o;
  }
}

// cast Wq/Wk/Wv [NL][512][512] into fused [NL][1536][512] at row-block blk
__global__ void cast_qkv_kernel(const float* __restrict__ src, u16* __restrict__ dst, int blk){
  int i = (blockIdx.x * 256 + threadIdx.x) * 4;
  if (i < NLn*Dd*Dd){
    int l = i >> 18, r = i & (Dd*Dd - 1);
    float4 v = *(const float4*)&src[i];
    ushort4 o; o.x = f2bf(v.x); o.y = f2bf(v.y); o.z = f2bf(v.z); o.w = f2bf(v.w);
    *(ushort4*)&dst[(size_t)l*(3*Dd*Dd) + (size_t)blk*Dd*Dd + r] = o;
  }
}

__global__ void bias_concat_kernel(const float* __restrict__ bq, const float* __restrict__ bk,
                                   const float* __restrict__ bv, float* __restrict__ dst){
  int i = blockIdx.x*256 + threadIdx.x;   // NL*512
  if (i < NLn*Dd){
    int l = i >> 9, r = i & 511;
    float* d = dst + (size_t)l*1536;
    d[r] = bq[i]; d[512+r] = bk[i]; d[1024+r] = bv[i];
  }
}

// ---------------- tau / delta projector (outputs pre-scaled, base-2, -16 shift) ----------------
#define SCL 0.180336880542795f   // 0.125 * log2(e)
__global__ void proj_kernel(const float* __restrict__ x_enc,
                            const float* __restrict__ Wtc, const float* __restrict__ Wt1, const float* __restrict__ bt1,
                            const float* __restrict__ Wt2, const float* __restrict__ bt2, const float* __restrict__ Wt3,
                            const float* __restrict__ Wdc, const float* __restrict__ Wd1, const float* __restrict__ bd1,
                            const float* __restrict__ Wd2, const float* __restrict__ bd2, const float* __restrict__ Wd3,
                            float* __restrict__ tau2, float* __restrict__ delta2){
  const int b = blockIdx.x, t = threadIdx.x;
  __shared__ float red[8][128];
  __shared__ float fv[8];
  __shared__ float ftau[4], fdel[4], h1t[128], h1d[128], h2t[128], h2d[128];
  float s0=0,s1=0,q0=0,q1=0,tc0=0,tc1=0,dc0=0,dc1=0;
  for (int s = t; s < Ss; s += 128){
    float x0 = x_enc[(b*Ss + s)*2 + 0];
    float x1 = x_enc[(b*Ss + s)*2 + 1];
    float wt0 = Wtc[s*3], wt1v = Wtc[s*3+1], wt2v = Wtc[s*3+2];
    float wd0 = Wdc[s*3], wd1v = Wdc[s*3+1], wd2v = Wdc[s*3+2];
    s0 += x0; s1 += x1; q0 += x0*x0; q1 += x1*x1;
    tc0 += x1*(wt0+wt2v) + x0*wt1v;
    tc1 += x0*(wt0+wt2v) + x1*wt1v;
    dc0 += x1*(wd0+wd2v) + x0*wd1v;
    dc1 += x0*(wd0+wd2v) + x1*wd1v;
  }
  red[0][t]=s0; red[1][t]=s1; red[2][t]=q0; red[3][t]=q1;
  red[4][t]=tc0; red[5][t]=tc1; red[6][t]=dc0; red[7][t]=dc1;
  __syncthreads();
  if (t < 8){ float a = 0; for (int i = 0; i < 128; i++) a += red[t][i]; fv[t] = a; }
  __syncthreads();
  if (t == 0){
    float m0 = fv[0]/Ss, m1 = fv[1]/Ss;
    float v0 = fv[2]/Ss - m0*m0, v1 = fv[3]/Ss - m1*m1;
    ftau[0]=fv[4]; ftau[1]=fv[5]; ftau[2]=sqrtf(v0+1e-5f); ftau[3]=sqrtf(v1+1e-5f);
    fdel[0]=fv[6]; fdel[1]=fv[7]; fdel[2]=m0; fdel[3]=m1;
  }
  __syncthreads();
  {
    float a = bt1[t], ad = bd1[t];
    #pragma unroll
    for (int j = 0; j < 4; j++){ a += Wt1[t*4+j]*ftau[j]; ad += Wd1[t*4+j]*fdel[j]; }
    h1t[t] = fmaxf(a, 0.f); h1d[t] = fmaxf(ad, 0.f);
  }
  __syncthreads();
  {
    float a = bt2[t], ad = bd2[t];
    for (int j = 0; j < 128; j++){ a += Wt2[t*128+j]*h1t[j]; ad += Wd2[t*128+j]*h1d[j]; }
    h2t[t] = fmaxf(a, 0.f); h2d[t] = fmaxf(ad, 0.f);
  }
  __syncthreads();
  if (t == 0){
    float z = 0; for (int j = 0; j < 128; j++) z += Wt3[j]*h2t[j];
    tau2[b] = expf(z) * SCL;
  }
  for (int s = t; s < Ss; s += 128){
    float z = 0; for (int j = 0; j < 128; j++) z += Wd3[s*128+j]*h2d[j];
    delta2[b*Ss + s] = z * SCL - 16.0f;
  }
}

// ---------------- embedding: circular conv + positional encoding ----------------
__global__ void embed_kernel(const float* __restrict__ xe, const float* __restrict__ Wemb,
                             float* __restrict__ xf, u16* __restrict__ xb){
  const int bs = blockIdx.x;          // b*S + s
  const int b = bs >> 9, s = bs & 511;
  const int t = threadIdx.x;          // 128 threads, 4 d each
  const int sm = (s + 511) & 511, sp = (s + 1) & 511;
  const float xm0 = xe[(b*Ss + sm)*2],   xm1 = xe[(b*Ss + sm)*2 + 1];
  const float x00 = xe[(b*Ss + s )*2],   x01 = xe[(b*Ss + s )*2 + 1];
  const float xp0 = xe[(b*Ss + sp)*2],   xp1 = xe[(b*Ss + sp)*2 + 1];
  #pragma unroll
  for (int dd = 0; dd < 4; dd++){
    const int d = t*4 + dd;
    const float* wd = Wemb + d*6;       // (D,2,3)
    float a = xm0*wd[0] + x00*wd[1] + xp0*wd[2]
            + xm1*wd[3] + x01*wd[4] + xp1*wd[5];
    const int i2 = d & ~1;
    float div = expf((float)i2 * (-9.210340371976184f / 512.0f));
    float ang = (float)s * div;
    float pe = (d & 1) ? cosf(ang) : sinf(ang);
    float v = a + pe;
    xf[(size_t)bs*Dd + d] = v;
    xb[(size_t)bs*Dd + d] = f2bf(v);
  }
}

// ---------------- GEMM: C[M,N] = A[M,K](bf16) * W[N,K]^T(bf16) + bias ----------------
// BK=64, 2-barrier compiler-scheduled loop, both-sides XOR chunk swizzle
// (source pre-swizzle for linear global_load_lds + swizzled frag reads,
// conflict-free: 2 lanes/bank), XCD-bijective grid swizzle, LDS-routed
// coalesced bf16 epilogue (pad 136). EPI: 0 = f32, 1 = bf16, 2 = bf16+gelu(tanh).
template<int EPI>
__global__ __launch_bounds__(256) void gemm_bt(const u16* __restrict__ A, const u16* __restrict__ W,
                                               const float* __restrict__ bias, void* __restrict__ Cv,
                                               int M, int N, int K, int ntx){
  __shared__ __attribute__((aligned(16))) u16 SM[16384];  // As[128*64] | Bs[128*64]
  u16* As = SM;
  u16* Bs = SM + 8192;
  const int tid = threadIdx.x;
  const int w = tid >> 6, l = tid & 63;
  const int wr = w >> 1, wc = w & 1;
  // ---- XCD-aware bijective tile swizzle ----
  const int nwg = gridDim.x;
  const int cpx = nwg >> 3;
  const int lin = blockIdx.x;
  const int g = (lin & 7)*cpx + (lin >> 3);
  const int by = g / ntx;
  const int bx = g - by*ntx;
  const long bm0 = (long)by * 128;
  const long bn0 = (long)bx * 128;
  // ---- staging: wave w owns rows w*32..+31; lane: row lr=l>>3, chunk lc=l&7 (16B) ----
  // source chunk pre-swizzled so LDS[row][c] = global chunk c ^ (row&7)
  const int lr = l >> 3, lc = l & 7;
  const int lcs = lc ^ lr;
  const u16* Ag = A + (bm0 + w*32 + lr) * (long)K + lcs*8;
  const u16* Bg = W + (bn0 + w*32 + lr) * (long)K + lcs*8;
  u16* AsW = As + w*2048;
  u16* BsW = Bs + w*2048;
  f32x4 acc[4][4] = {};
  const int aro = wr*64 + (l & 15);
  const int bro = wc*64 + (l & 15);
  const int l4 = l >> 4;
  const int rsw = (l & 15) & 7;          // row&7 for all frag rows (16-aligned offsets)
  for (int kt = 0; kt < K; kt += 64){
    #pragma unroll
    for (int i = 0; i < 4; i++){
      gload16(Ag + kt + i*8*(long)K, AsW + i*512);
      gload16(Bg + kt + i*8*(long)K, BsW + i*512);
    }
    __syncthreads();   // compiler drains vmcnt: staged tile visible
    #pragma unroll
    for (int kk = 0; kk < 2; kk++){
      const int ck = ((kk*4 + l4) ^ rsw) * 8;
      bf16x8 af[4], bfv[4];
      #pragma unroll
      for (int mi = 0; mi < 4; mi++) af[mi] = *(const bf16x8*)&As[(aro + mi*16)*64 + ck];
      #pragma unroll
      for (int ni = 0; ni < 4; ni++) bfv[ni] = *(const bf16x8*)&Bs[(bro + ni*16)*64 + ck];
      #pragma unroll
      for (int mi = 0; mi < 4; mi++)
        #pragma unroll
        for (int ni = 0; ni < 4; ni++)
          acc[mi][ni] = mfma16(af[mi], bfv[ni], acc[mi][ni]);
    }
    __syncthreads();   // all waves done reading before next stage overwrites
  }
  if (EPI == 0){
    // f32 direct stores (64B segments per 16 lanes, no amplification)
    const long rbase = bm0 + wr*64 + (l >> 4)*4;
    const int cbase = (int)bn0 + wc*64 + (l & 15);
    #pragma unroll
    for (int ni = 0; ni < 4; ni++){
      const int c = cbase + ni*16;
      const float bvv = bias[c];
      #pragma unroll
      for (int mi = 0; mi < 4; mi++)
        #pragma unroll
        for (int j = 0; j < 4; j++)
          ((float*)Cv)[(size_t)(rbase + mi*16 + j) * N + c] = acc[mi][ni][j] + bvv;
    }
  } else {
    // bf16: route through LDS (pad 136 -> 4-bank row rotation) for 256B row stores
    u16* CT = SM;                 // 64x136 u16 = 17.4 KB (reuses As|Bs)
    float bvv[4];
    #pragma unroll
    for (int ni = 0; ni < 4; ni++) bvv[ni] = bias[bn0 + wc*64 + ni*16 + (l & 15)];
    u16* Cu = (u16*)Cv;
    #pragma unroll
    for (int h = 0; h < 2; h++){
      __syncthreads();
      #pragma unroll
      for (int mi2 = 0; mi2 < 2; mi2++){
        const int mi = 2*h + mi2;
        #pragma unroll
        for (int ni = 0; ni < 4; ni++){
          #pragma unroll
          for (int j = 0; j < 4; j++){
            float v = acc[mi][ni][j] + bvv[ni];
            if (EPI == 2) v = gelu_t(v);
            CT[(wr*32 + mi2*16 + (l >> 4)*4 + j)*136 + wc*64 + ni*16 + (l & 15)] = f2bf(v);
          }
        }
      }
      __syncthreads();
      #pragma unroll
      for (int p = 0; p < 4; p++){
        const int r = (tid >> 4) + p*16;
        const long grow = bm0 + (r >> 5)*64 + h*32 + (r & 31);
        *(bf16x8*)&Cu[(size_t)grow * N + bn0 + (tid & 15)*8] =
            *(const bf16x8*)&CT[r*136 + (tid & 15)*8];
      }
    }
  }
}

// ---------------- fused flash attention, one block per (b,h) ----------------
__global__ __launch_bounds__(512, 2) void attn_kernel(const u16* __restrict__ qkv,
                                                      const float* __restrict__ tau2,
                                                      const float* __restrict__ delta2,
                                                      u16* __restrict__ Ob){
  const int bid = blockIdx.x;
  const int h = bid & 7, b = bid >> 3;
  const int t = threadIdx.x, w = t >> 6, l = t & 63;
  const int l15 = l & 15, l4 = l >> 4;
  __shared__ __attribute__((aligned(16))) u16 Ks[512*64];      // 64 KB, XOR swizzle
  __shared__ __attribute__((aligned(16))) u16 Vt[64*520];      // 65 KB, pad 520
  __shared__ __attribute__((aligned(16))) u16 Ps[8][16*72];    // 18 KB, per-wave
  const size_t qkvbase = ((size_t)b*Ss)*1536 + h*64;
  {
    const u16* Kg = qkv + qkvbase + 512  + (size_t)t*1536;
    const u16* Vg = qkv + qkvbase + 1024 + (size_t)t*1536;
    #pragma unroll
    for (int c = 0; c < 8; c++){
      bf16x8 kv = *(const bf16x8*)&Kg[c*8];
      const int byte = t*128 + ((c*16) ^ ((t & 7) << 4));
      *(bf16x8*)((char*)Ks + byte) = kv;
    }
    union { bf16x8 v[8]; u16 e[64]; } vv;
    #pragma unroll
    for (int c = 0; c < 8; c++) vv.v[c] = *(const bf16x8*)&Vg[c*8];
    #pragma unroll
    for (int e = 0; e < 64; e++) Vt[e*520 + t] = vv.e[e];
  }
  const int q0 = w*64;
  bf16x8 qa[4][2];
  #pragma unroll
  for (int mi = 0; mi < 4; mi++)
    #pragma unroll
    for (int ks = 0; ks < 2; ks++)
      qa[mi][ks] = *(const bf16x8*)&qkv[qkvbase + (size_t)(q0 + mi*16 + l15)*1536 + ks*32 + l4*8];
  const float ts = tau2[b];
  bf16x8 ones8;
  #pragma unroll
  for (int i = 0; i < 8; i++) ones8[i] = (short)0x3F80;
  __syncthreads();

  f32x4 Oa[4][4] = {};
  f32x4 Ls[4] = {};
  u16* PsW = Ps[w];
  for (int kt = 0; kt < 8; kt++){
    f32x4 sc[4][4] = {};
    #pragma unroll
    for (int ni = 0; ni < 4; ni++){
      const int krow = kt*64 + ni*16 + l15;
      const int swz = (krow & 7) << 4;
      bf16x8 kf0 = *(const bf16x8*)((const char*)Ks + krow*128 + ((l4*16)      ^ swz));
      bf16x8 kf1 = *(const bf16x8*)((const char*)Ks + krow*128 + ((64 + l4*16) ^ swz));
      #pragma unroll
      for (int mi = 0; mi < 4; mi++){
        sc[mi][ni] = mfma16(qa[mi][0], kf0, sc[mi][ni]);
        sc[mi][ni] = mfma16(qa[mi][1], kf1, sc[mi][ni]);
      }
    }
    float dl[4];
    #pragma unroll
    for (int ni = 0; ni < 4; ni++) dl[ni] = delta2[b*Ss + kt*64 + ni*16 + l15];
    bf16x8 pa[4][2];
    #pragma unroll
    for (int mi = 0; mi < 4; mi++){
      #pragma unroll
      for (int ni = 0; ni < 4; ni++){
        #pragma unroll
        for (int j = 0; j < 4; j++){
          float p = exp2f(ts * sc[mi][ni][j] + dl[ni]);
          PsW[(l4*4 + j)*72 + ni*16 + l15] = f2bf(p);
        }
      }
      pa[mi][0] = *(const bf16x8*)&PsW[l15*72 +      l4*8];
      pa[mi][1] = *(const bf16x8*)&PsW[l15*72 + 32 + l4*8];
    }
    #pragma unroll
    for (int ni = 0; ni < 4; ni++){
      const int vrow = ni*16 + l15;
      bf16x8 vf0 = *(const bf16x8*)&Vt[vrow*520 + kt*64 +      l4*8];
      bf16x8 vf1 = *(const bf16x8*)&Vt[vrow*520 + kt*64 + 32 + l4*8];
      #pragma unroll
      for (int mi = 0; mi < 4; mi++){
        Oa[mi][ni] = mfma16(pa[mi][0], vf0, Oa[mi][ni]);
        Oa[mi][ni] = mfma16(pa[mi][1], vf1, Oa[mi][ni]);
      }
    }
    #pragma unroll
    for (int mi = 0; mi < 4; mi++){
      Ls[mi] = mfma16(pa[mi][0], ones8, Ls[mi]);
      Ls[mi] = mfma16(pa[mi][1], ones8, Ls[mi]);
    }
  }
  const size_t obase = (size_t)b*Ss*Dd + h*64;
  #pragma unroll
  for (int mi = 0; mi < 4; mi++){
    f32x4 rv;
    #pragma unroll
    for (int j = 0; j < 4; j++) rv[j] = 1.0f / Ls[mi][j];
    #pragma unroll
    for (int ni = 0; ni < 4; ni++)
      #pragma unroll
      for (int j = 0; j < 4; j++)
        Ob[obase + (size_t)(q0 + mi*16 + l4*4 + j)*Dd + ni*16 + l15] = f2bf(Oa[mi][ni][j] * rv[j]);
  }
}

// ---------------- fused residual + LayerNorm (float4) ----------------
__global__ void ln_residual_kernel(float* __restrict__ xf, const float* __restrict__ tf,
                                   const float* __restrict__ g, const float* __restrict__ bln,
                                   u16* __restrict__ xb){
  const int row = blockIdx.x, t = threadIdx.x;   // 128 threads
  const size_t base = (size_t)row * Dd + t*4;
  float4 a = *(const float4*)&xf[base];
  const float4 dv = *(const float4*)&tf[base];
  a.x += dv.x; a.y += dv.y; a.z += dv.z; a.w += dv.w;
  float sum = a.x + a.y + a.z + a.w;
  float sq  = a.x*a.x + a.y*a.y + a.z*a.z + a.w*a.w;
  #pragma unroll
  for (int off = 32; off >= 1; off >>= 1){ sum += __shfl_down(sum, off); sq += __shfl_down(sq, off); }
  __shared__ float sh[4];
  const int w = t >> 6, l = t & 63;
  if (l == 0){ sh[w] = sum; sh[2+w] = sq; }
  __syncthreads();
  sum = sh[0] + sh[1]; sq = sh[2] + sh[3];
  const float mean = sum * (1.f/Dd);
  const float var  = sq * (1.f/Dd) - mean*mean;
  const float rstd = rsqrtf(var + 1e-5f);
  const float4 gg = *(const float4*)&g[t*4];
  const float4 bb = *(const float4*)&bln[t*4];
  float4 y;
  y.x = (a.x - mean)*rstd*gg.x + bb.x;
  y.y = (a.y - mean)*rstd*gg.y + bb.y;
  y.z = (a.z - mean)*rstd*gg.z + bb.z;
  y.w = (a.w - mean)*rstd*gg.w + bb.w;
  *(float4*)&xf[base] = y;
  ushort4 o; o.x = f2bf(y.x); o.y = f2bf(y.y); o.z = f2bf(y.z); o.w = f2bf(y.w);
  *(ushort4*)&xb[base] = o;
}

// ---------------- final LN + gelu + Wout dot ----------------
__global__ void final_kernel(const float* __restrict__ xf, const float* __restrict__ gn, const float* __restrict__ bn,
                             const float* __restrict__ Wout, const float* __restrict__ bout,
                             float* __restrict__ out){
  const int row = blockIdx.x, t = threadIdx.x;
  const size_t base = (size_t)row * Dd;
  const int i = t*2;
  float x0 = xf[base+i], x1 = xf[base+i+1];
  float sum = x0 + x1, sq = x0*x0 + x1*x1;
  #pragma unroll
  for (int off = 32; off >= 1; off >>= 1){ sum += __shfl_down(sum, off); sq += __shfl_down(sq, off); }
  __shared__ float sh[8];
  __shared__ float sh2[4];
  const int w = t >> 6, l = t & 63;
  if (l == 0){ sh[w] = sum; sh[4+w] = sq; }
  __syncthreads();
  sum = sh[0]+sh[1]+sh[2]+sh[3];
  sq  = sh[4]+sh[5]+sh[6]+sh[7];
  const float mean = sum * (1.f/Dd);
  const float var  = sq * (1.f/Dd) - mean*mean;
  const float rstd = rsqrtf(var + 1e-5f);
  float y0 = (x0 - mean)*rstd*gn[i]   + bn[i];
  float y1 = (x1 - mean)*rstd*gn[i+1] + bn[i+1];
  float p = gelu_f(y0)*Wout[i] + gelu_f(y1)*Wout[i+1];
  #pragma unroll
  for (int off = 32; off >= 1; off >>= 1) p += __shfl_down(p, off);
  if (l == 0) sh2[w] = p;
  __syncthreads();
  if (t == 0) out[row] = sh2[0]+sh2[1]+sh2[2]+sh2[3] + bout[0];
}

extern "C" void kernel_launch(void* const* d_in, const int* in_sizes, int n_in,
                              void* d_out, int out_size, void* d_ws, size_t ws_size,
                              hipStream_t stream){
  (void)in_sizes; (void)n_in; (void)out_size; (void)ws_size;
  const float* x_enc = (const float*)d_in[0];
  const float* W_emb = (const float*)d_in[1];
  const float* Wq  = (const float*)d_in[2];
  const float* bq  = (const float*)d_in[3];
  const float* Wk  = (const float*)d_in[4];
  const float* bk  = (const float*)d_in[5];
  const float* Wv  = (const float*)d_in[6];
  const float* bvp = (const float*)d_in[7];
  const float* Wo  = (const float*)d_in[8];
  const float* bo  = (const float*)d_in[9];
  const float* Wc1 = (const float*)d_in[10];
  const float* bc1 = (const float*)d_in[11];
  const float* Wc2 = (const float*)d_in[12];
  const float* bc2 = (const float*)d_in[13];
  const float* g1  = (const float*)d_in[14];
  const float* be1 = (const float*)d_in[15];
  const float* g2  = (const float*)d_in[16];
  const float* be2 = (const float*)d_in[17];
  const float* gn  = (const float*)d_in[18];
  const float* bn  = (const float*)d_in[19];
  const float* Wout= (const float*)d_in[20];
  const float* bout= (const float*)d_in[21];
  const float* Wtc = (const float*)d_in[22];
  const float* Wt1 = (const float*)d_in[23];
  const float* bt1 = (const float*)d_in[24];
  const float* Wt2 = (const float*)d_in[25];
  const float* bt2 = (const float*)d_in[26];
  const float* Wt3 = (const float*)d_in[27];
  const float* Wdc = (const float*)d_in[28];
  const float* Wd1 = (const float*)d_in[29];
  const float* bd1 = (const float*)d_in[30];
  const float* Wd2 = (const float*)d_in[31];
  const float* bd2 = (const float*)d_in[32];
  const float* Wd3 = (const float*)d_in[33];

  char* ws = (char*)d_ws;
  size_t off = 0;
  auto alloc = [&](size_t nbytes) -> void* {
    void* p = ws + off; off += (nbytes + 255) & ~(size_t)255; return p;
  };
  const size_t BSD = (size_t)Bb*Ss*Dd;
  u16* Wqkv_b = (u16*)alloc((size_t)NLn*3*Dd*Dd*2);
  u16* Wo_b   = (u16*)alloc((size_t)NLn*Dd*Dd*2);
  u16* Wc1_b  = (u16*)alloc((size_t)NLn*DFf*Dd*2);
  u16* Wc2_b  = (u16*)alloc((size_t)NLn*Dd*DFf*2);
  float* bqkv = (float*)alloc((size_t)NLn*3*Dd*4);
  float* xf   = (float*)alloc(BSD*4);
  u16*   xb   = (u16*)alloc(BSD*2);
  u16*   qkvb = (u16*)alloc(BSD*3*2);
  u16*   ab   = (u16*)alloc(BSD*2);
  float* tf   = (float*)alloc(BSD*4);
  u16*   hb   = (u16*)alloc((size_t)Bb*Ss*DFf*2);
  float* tau2   = (float*)alloc(Bb*4);
  float* delta2 = (float*)alloc((size_t)Bb*Ss*4);

  const int nW = NLn*Dd*Dd;       // 1,572,864
  const int nC = NLn*DFf*Dd;      // 6,291,456
  cast_qkv_kernel<<<nW/1024, 256, 0, stream>>>(Wq, Wqkv_b, 0);
  cast_qkv_kernel<<<nW/1024, 256, 0, stream>>>(Wk, Wqkv_b, 1);
  cast_qkv_kernel<<<nW/1024, 256, 0, stream>>>(Wv, Wqkv_b, 2);
  cast_kernel<<<nW/1024, 256, 0, stream>>>(Wo,  Wo_b,  nW);
  cast_kernel<<<nC/1024, 256, 0, stream>>>(Wc1, Wc1_b, nC);
  cast_kernel<<<nC/1024, 256, 0, stream>>>(Wc2, Wc2_b, nC);
  bias_concat_kernel<<<(NLn*Dd + 255)/256, 256, 0, stream>>>(bq, bk, bvp, bqkv);

  proj_kernel<<<Bb, 128, 0, stream>>>(x_enc, Wtc, Wt1, bt1, Wt2, bt2, Wt3,
                                      Wdc, Wd1, bd1, Wd2, bd2, Wd3, tau2, delta2);
  embed_kernel<<<Bb*Ss, 128, 0, stream>>>(x_enc, W_emb, xf, xb);

  const int M = Bb*Ss;
  const int nQKV = (3*Dd/128)*(M/128);   // 12*128 = 1536
  const int n512 = (Dd/128)*(M/128);     // 4*128  = 512
  const int nFF1 = (DFf/128)*(M/128);    // 16*128 = 2048
  for (int lyr = 0; lyr < NLn; lyr++){
    const u16* wqkv = Wqkv_b + (size_t)lyr*3*Dd*Dd;
    const u16* wo = Wo_b  + (size_t)lyr*Dd*Dd;
    const u16* w1 = Wc1_b + (size_t)lyr*DFf*Dd;
    const u16* w2 = Wc2_b + (size_t)lyr*Dd*DFf;
    gemm_bt<1><<<nQKV, 256, 0, stream>>>(xb, wqkv, bqkv + (size_t)lyr*3*Dd, qkvb, M, 3*Dd, Dd, 3*Dd/128);
    attn_kernel<<<Bb*Hh, 512, 0, stream>>>(qkvb, tau2, delta2, ab);
    gemm_bt<0><<<n512, 256, 0, stream>>>(ab, wo, bo + lyr*Dd, tf, M, Dd, Dd, Dd/128);
    ln_residual_kernel<<<M, 128, 0, stream>>>(xf, tf, g1 + lyr*Dd, be1 + lyr*Dd, xb);
    gemm_bt<2><<<nFF1, 256, 0, stream>>>(xb, w1, bc1 + lyr*DFf, hb, M, DFf, Dd, DFf/128);
    gemm_bt<0><<<n512, 256, 0, stream>>>(hb, w2, bc2 + lyr*Dd, tf, M, Dd, DFf, Dd/128);
    ln_residual_kernel<<<M, 128, 0, stream>>>(xf, tf, g2 + lyr*Dd, be2 + lyr*Dd, xb);
  }
  final_kernel<<<M, 256, 0, stream>>>(xf, gn, bn, Wout, bout, (float*)d_out);
}